// Round 1
// baseline (1083.814 us; speedup 1.0000x reference)
//
#include <hip/hip_runtime.h>

#define NN 100000
#define NE 1000000
#define D 64

// ---------------- gcn_norm ----------------

__global__ void deg_kernel(const int* __restrict__ col, const float* __restrict__ ew,
                           float* __restrict__ deg, int E) {
    int e = blockIdx.x * blockDim.x + threadIdx.x;
    if (e < E) atomicAdd(&deg[col[e]], ew[e]);
}

// in-place: deg -> dinv = rsqrt(deg + 1)   (self loop adds 1.0; always > 0)
__global__ void dinv_kernel(float* __restrict__ deg, int n) {
    int i = blockIdx.x * blockDim.x + threadIdx.x;
    if (i < n) deg[i] = rsqrtf(deg[i] + 1.0f);
}

__global__ void norm_kernel(const int* __restrict__ row, const int* __restrict__ col,
                            const float* __restrict__ ew, const float* __restrict__ dinv,
                            float* __restrict__ nrm, int E) {
    int e = blockIdx.x * blockDim.x + threadIdx.x;
    if (e < E) nrm[e] = dinv[row[e]] * ew[e] * dinv[col[e]];
}

// ---------------- dense transform: out[n,0:64] = H[n,:] @ W (64x64) ----------------
// 256 threads, 16 rows per block. W staged in LDS (16KB), H rows in LDS (4KB).
__global__ void gemm_n64(const float* __restrict__ H, const float* __restrict__ W,
                         float* __restrict__ out, int n) {
    __shared__ float Ws[D][D];
    __shared__ float Hs[16][D];
    int tid = threadIdx.x;
    for (int i = tid; i < D * D; i += 256) Ws[i >> 6][i & 63] = W[i];
    int base = blockIdx.x * 16;
    for (int i = tid; i < 16 * D; i += 256) {
        int r = i >> 6, k = i & 63;
        int node = base + r;
        Hs[r][k] = (node < n) ? H[node * D + k] : 0.0f;
    }
    __syncthreads();
    int j = tid & 63;
    int r0 = tid >> 6;  // 0..3
#pragma unroll
    for (int rr = 0; rr < 4; ++rr) {
        int r = r0 * 4 + rr;
        int node = base + r;
        if (node < n) {
            float acc = 0.0f;
#pragma unroll
            for (int k = 0; k < D; ++k) acc = fmaf(Hs[r][k], Ws[k][j], acc);
            out[node * D + j] = acc;
        }
    }
}

// ---------------- edge scatter: acc[col] += norm * hw[row] (64 feats / edge, 1 wave / edge) ----------------
__global__ void scatter64_kernel(const int* __restrict__ row, const int* __restrict__ col,
                                 const float* __restrict__ nrm, const float* __restrict__ hw,
                                 float* __restrict__ acc, int E) {
    int e = blockIdx.x * 4 + (threadIdx.x >> 6);
    if (e >= E) return;
    int j = threadIdx.x & 63;
    int r = row[e];
    int c = col[e];
    float v = nrm[e] * hw[r * D + j];
    atomicAdd(&acc[c * D + j], v);
}

// ---------------- combine: h_out = act(acc + dinv^2*hw + b [+ hres]) ----------------
__global__ void combine_kernel(const float* __restrict__ acc, const float* __restrict__ hw,
                               const float* __restrict__ dinv, const float* __restrict__ b,
                               const float* __restrict__ hres, float* __restrict__ hout,
                               int n) {
    int idx = blockIdx.x * 256 + threadIdx.x;
    if (idx >= n * D) return;
    int node = idx >> 6;
    int j = idx & 63;
    float d = dinv[node];
    float v = acc[idx] + d * d * hw[idx] + b[j];
    if (hres) v += hres[idx];
    v = fmaxf(v, 0.0f);
    hout[idx] = v;
}

// ---------------- final layer: hwf[n] = dot(H[n,:], Wf) ----------------
__global__ void gemv_final(const float* __restrict__ H, const float* __restrict__ Wf,
                           float* __restrict__ hwf, int n) {
    int node = blockIdx.x * 4 + (threadIdx.x >> 6);
    if (node >= n) return;
    int k = threadIdx.x & 63;
    float v = H[node * D + k] * Wf[k];
#pragma unroll
    for (int off = 32; off > 0; off >>= 1) v += __shfl_down(v, off, 64);
    if (k == 0) hwf[node] = v;
}

__global__ void scatter1_kernel(const int* __restrict__ row, const int* __restrict__ col,
                                const float* __restrict__ nrm, const float* __restrict__ hwf,
                                float* __restrict__ out, int E) {
    int e = blockIdx.x * blockDim.x + threadIdx.x;
    if (e < E) atomicAdd(&out[col[e]], nrm[e] * hwf[row[e]]);
}

__global__ void final_add_kernel(float* __restrict__ out, const float* __restrict__ hwf,
                                 const float* __restrict__ dinv, const float* __restrict__ bf,
                                 int n) {
    int i = blockIdx.x * blockDim.x + threadIdx.x;
    if (i < n) {
        float d = dinv[i];
        out[i] += d * d * hwf[i] + bf[0];
    }
}

extern "C" void kernel_launch(void* const* d_in, const int* in_sizes, int n_in,
                              void* d_out, int out_size, void* d_ws, size_t ws_size,
                              hipStream_t stream) {
    const float* x    = (const float*)d_in[0];
    const int*   ei   = (const int*)d_in[1];      // [2, E] flat: row then col
    const float* ew   = (const float*)d_in[2];
    // d_in[3] = batch (unused)
    const float* W_in = (const float*)d_in[4];
    const float* b_in = (const float*)d_in[5];
    const float* W1   = (const float*)d_in[6];
    const float* b1   = (const float*)d_in[7];
    const float* W2   = (const float*)d_in[8];
    const float* b2   = (const float*)d_in[9];
    const float* Wf   = (const float*)d_in[10];
    const float* bf   = (const float*)d_in[11];
    float* out = (float*)d_out;

    const int E = NE, n = NN;
    const int* row = ei;
    const int* col = ei + E;

    // workspace carve-up (floats), 256B-aligned chunks
    char* ws = (char*)d_ws;
    size_t off = 0;
    auto alloc = [&](size_t nfloats) {
        float* p = (float*)(ws + off);
        off += ((nfloats * sizeof(float) + 255) / 256) * 256;
        return p;
    };
    float* dinv = alloc(n);        // deg -> dinv in place
    float* nrm  = alloc(E);
    float* hw   = alloc((size_t)n * D);
    float* hA   = alloc((size_t)n * D);
    float* hB   = alloc((size_t)n * D);
    float* acc  = alloc((size_t)n * D);
    float* hwf  = alloc(n);

    const size_t ND_bytes = (size_t)n * D * sizeof(float);

    // ---- gcn_norm ----
    hipMemsetAsync(dinv, 0, n * sizeof(float), stream);
    deg_kernel<<<(E + 255) / 256, 256, 0, stream>>>(col, ew, dinv, E);
    dinv_kernel<<<(n + 255) / 256, 256, 0, stream>>>(dinv, n);
    norm_kernel<<<(E + 255) / 256, 256, 0, stream>>>(row, col, ew, dinv, nrm, E);

    const int gemm_grid = (n + 15) / 16;
    const int scat_grid = (E + 3) / 4;
    const int comb_grid = (n * D + 255) / 256;

    // ---- layer 1: hA = relu(conv(x, W_in, b_in)) ----
    hipMemsetAsync(acc, 0, ND_bytes, stream);
    gemm_n64<<<gemm_grid, 256, 0, stream>>>(x, W_in, hw, n);
    scatter64_kernel<<<scat_grid, 256, 0, stream>>>(row, col, nrm, hw, acc, E);
    combine_kernel<<<comb_grid, 256, 0, stream>>>(acc, hw, dinv, b_in, nullptr, hA, n);

    // ---- layer 2: hB = relu(conv(hA, W1, b1) + hA) ----
    hipMemsetAsync(acc, 0, ND_bytes, stream);
    gemm_n64<<<gemm_grid, 256, 0, stream>>>(hA, W1, hw, n);
    scatter64_kernel<<<scat_grid, 256, 0, stream>>>(row, col, nrm, hw, acc, E);
    combine_kernel<<<comb_grid, 256, 0, stream>>>(acc, hw, dinv, b1, hA, hB, n);

    // ---- layer 3: hA = relu(conv(hB, W2, b2) + hB) ----
    hipMemsetAsync(acc, 0, ND_bytes, stream);
    gemm_n64<<<gemm_grid, 256, 0, stream>>>(hB, W2, hw, n);
    scatter64_kernel<<<scat_grid, 256, 0, stream>>>(row, col, nrm, hw, acc, E);
    combine_kernel<<<comb_grid, 256, 0, stream>>>(acc, hw, dinv, b2, hB, hA, n);

    // ---- final: out = conv(hA, Wf, bf)  [N,1] ----
    hipMemsetAsync(out, 0, n * sizeof(float), stream);
    gemv_final<<<(n + 3) / 4, 256, 0, stream>>>(hA, Wf, hwf, n);
    scatter1_kernel<<<(E + 255) / 256, 256, 0, stream>>>(row, col, nrm, hwf, out, E);
    final_add_kernel<<<(n + 255) / 256, 256, 0, stream>>>(out, hwf, dinv, bf, n);
}

// Round 2
// 655.607 us; speedup vs baseline: 1.6531x; 1.6531x over previous
//
#include <hip/hip_runtime.h>

#define NN 100000
#define NE 1000000
#define D 64

// ---------------- degree + count ----------------
__global__ void deg_cnt_kernel(const int* __restrict__ col, const float* __restrict__ ew,
                               float* __restrict__ degw, int* __restrict__ cnt, int E) {
    int e = blockIdx.x * blockDim.x + threadIdx.x;
    if (e < E) {
        int c = col[e];
        atomicAdd(&degw[c], ew[e]);
        atomicAdd(&cnt[c], 1);
    }
}

// in-place: degw -> dinv = rsqrt(degw + 1)   (self loop adds 1.0; always > 0)
__global__ void dinv_kernel(float* __restrict__ degw, int n) {
    int i = blockIdx.x * blockDim.x + threadIdx.x;
    if (i < n) degw[i] = rsqrtf(degw[i] + 1.0f);
}

// ---------------- two-level exclusive scan of cnt -> rowptr ----------------
// A: per-block (256 elems) exclusive scan; block total -> bsum[b]
__global__ void scanA(const int* __restrict__ cnt, int* __restrict__ rowptr,
                      int* __restrict__ bsum, int n) {
    __shared__ int s[256];
    int t = threadIdx.x;
    int i = blockIdx.x * 256 + t;
    int orig = (i < n) ? cnt[i] : 0;
    s[t] = orig;
    __syncthreads();
#pragma unroll
    for (int o = 1; o < 256; o <<= 1) {
        int v = (t >= o) ? s[t - o] : 0;
        __syncthreads();
        s[t] += v;
        __syncthreads();
    }
    if (i < n) rowptr[i] = s[t] - orig;            // exclusive within block
    if (t == 255) bsum[blockIdx.x] = s[t];         // block total
}

// B: single block scans bsum (<=512 entries) -> exclusive
__global__ void scanB(int* __restrict__ bsum, int nb) {
    __shared__ int s[512];
    int t = threadIdx.x;
    int orig = (t < nb) ? bsum[t] : 0;
    s[t] = orig;
    __syncthreads();
#pragma unroll
    for (int o = 1; o < 512; o <<= 1) {
        int v = (t >= o) ? s[t - o] : 0;
        __syncthreads();
        s[t] += v;
        __syncthreads();
    }
    if (t < nb) bsum[t] = s[t] - orig;             // exclusive
}

// C: add block offsets; init cursor = rowptr
__global__ void scanC(int* __restrict__ rowptr, const int* __restrict__ bsum,
                      int* __restrict__ cursor, int n) {
    int i = blockIdx.x * 256 + threadIdx.x;
    if (i < n) {
        int v = rowptr[i] + bsum[i >> 8];
        rowptr[i] = v;
        cursor[i] = v;
    }
}

// ---------------- placement: sort edges by col, computing norm on the fly ----------------
__global__ void place_kernel(const int* __restrict__ row, const int* __restrict__ col,
                             const float* __restrict__ ew, const float* __restrict__ dinv,
                             int* __restrict__ cursor, int* __restrict__ srow,
                             float* __restrict__ snorm, int E) {
    int e = blockIdx.x * blockDim.x + threadIdx.x;
    if (e < E) {
        int r = row[e], c = col[e];
        float w = dinv[r] * ew[e] * dinv[c];
        int pos = atomicAdd(&cursor[c], 1);
        srow[pos] = r;
        snorm[pos] = w;
    }
}

// ---------------- dense transform: out[n,0:64] = H[n,:] @ W (64x64) ----------------
__global__ void gemm_n64(const float* __restrict__ H, const float* __restrict__ W,
                         float* __restrict__ out, int n) {
    __shared__ float Ws[D][D];
    __shared__ float Hs[16][D];
    int tid = threadIdx.x;
    for (int i = tid; i < D * D; i += 256) Ws[i >> 6][i & 63] = W[i];
    int base = blockIdx.x * 16;
    for (int i = tid; i < 16 * D; i += 256) {
        int r = i >> 6, k = i & 63;
        int node = base + r;
        Hs[r][k] = (node < n) ? H[node * D + k] : 0.0f;
    }
    __syncthreads();
    int j = tid & 63;
    int r0 = tid >> 6;  // 0..3
#pragma unroll
    for (int rr = 0; rr < 4; ++rr) {
        int r = r0 * 4 + rr;
        int node = base + r;
        if (node < n) {
            float acc = 0.0f;
#pragma unroll
            for (int k = 0; k < D; ++k) acc = fmaf(Hs[r][k], Ws[k][j], acc);
            out[node * D + j] = acc;
        }
    }
}

// ---------------- fused gather + self-loop + bias + residual + relu ----------------
// one wave per dest node; lane = feature
__global__ void gather64_kernel(const int* __restrict__ rowptr, const int* __restrict__ cnt,
                                const int* __restrict__ srow, const float* __restrict__ snorm,
                                const float* __restrict__ hw, const float* __restrict__ dinv,
                                const float* __restrict__ b, const float* __restrict__ hres,
                                float* __restrict__ hout, int n) {
    int c = blockIdx.x * 4 + (threadIdx.x >> 6);
    if (c >= n) return;
    int j = threadIdx.x & 63;
    int start = rowptr[c];
    int deg = cnt[c];
    float acc = 0.0f;
    for (int base = 0; base < deg; base += 64) {
        int m = deg - base; if (m > 64) m = 64;
        int er = 0; float en = 0.0f;
        if (base + j < deg) {
            er = srow[start + base + j];
            en = snorm[start + base + j];
        }
        for (int t = 0; t < m; ++t) {
            int r = __shfl(er, t, 64);
            float w = __shfl(en, t, 64);
            acc = fmaf(w, hw[r * D + j], acc);
        }
    }
    float d = dinv[c];
    float v = acc + d * d * hw[c * D + j] + b[j];
    if (hres) v += hres[c * D + j];
    hout[c * D + j] = fmaxf(v, 0.0f);
}

// ---------------- final layer ----------------
__global__ void gemv_final(const float* __restrict__ H, const float* __restrict__ Wf,
                           float* __restrict__ hwf, int n) {
    int node = blockIdx.x * 4 + (threadIdx.x >> 6);
    if (node >= n) return;
    int k = threadIdx.x & 63;
    float v = H[node * D + k] * Wf[k];
#pragma unroll
    for (int off = 32; off > 0; off >>= 1) v += __shfl_down(v, off, 64);
    if (k == 0) hwf[node] = v;
}

__global__ void gather1_kernel(const int* __restrict__ rowptr, const int* __restrict__ cnt,
                               const int* __restrict__ srow, const float* __restrict__ snorm,
                               const float* __restrict__ hwf, const float* __restrict__ dinv,
                               const float* __restrict__ bf, float* __restrict__ out, int n) {
    int c = blockIdx.x * blockDim.x + threadIdx.x;
    if (c >= n) return;
    int start = rowptr[c];
    int end = start + cnt[c];
    float acc = 0.0f;
    for (int e = start; e < end; ++e) acc += snorm[e] * hwf[srow[e]];
    float d = dinv[c];
    out[c] = acc + d * d * hwf[c] + bf[0];
}

extern "C" void kernel_launch(void* const* d_in, const int* in_sizes, int n_in,
                              void* d_out, int out_size, void* d_ws, size_t ws_size,
                              hipStream_t stream) {
    const float* x    = (const float*)d_in[0];
    const int*   ei   = (const int*)d_in[1];      // [2, E] flat: row then col
    const float* ew   = (const float*)d_in[2];
    const float* W_in = (const float*)d_in[4];
    const float* b_in = (const float*)d_in[5];
    const float* W1   = (const float*)d_in[6];
    const float* b1   = (const float*)d_in[7];
    const float* W2   = (const float*)d_in[8];
    const float* b2   = (const float*)d_in[9];
    const float* Wf   = (const float*)d_in[10];
    const float* bf   = (const float*)d_in[11];
    float* out = (float*)d_out;

    const int E = NE, n = NN;
    const int* row = ei;
    const int* col = ei + E;

    // workspace carve-up, 256B-aligned chunks
    char* ws = (char*)d_ws;
    size_t off = 0;
    auto alloc = [&](size_t nelems) {
        void* p = (void*)(ws + off);
        off += ((nelems * 4 + 255) / 256) * 256;
        return p;
    };
    float* dinv   = (float*)alloc(n);
    int*   cnt    = (int*)alloc(n);
    int*   rowptr = (int*)alloc(n);
    int*   cursor = (int*)alloc(n);
    int*   bsum   = (int*)alloc(512);
    int*   srow   = (int*)alloc(E);
    float* snorm  = (float*)alloc(E);
    float* hw     = (float*)alloc((size_t)n * D);
    float* hA     = (float*)alloc((size_t)n * D);
    float* hB     = (float*)alloc((size_t)n * D);
    float* hwf    = (float*)alloc(n);

    const int nbA = (n + 255) / 256;   // 391 scan blocks (<=512)

    // ---- gcn_norm + CSR build ----
    hipMemsetAsync(dinv, 0, n * sizeof(float), stream);
    hipMemsetAsync(cnt, 0, n * sizeof(int), stream);
    deg_cnt_kernel<<<(E + 255) / 256, 256, 0, stream>>>(col, ew, dinv, cnt, E);
    dinv_kernel<<<nbA, 256, 0, stream>>>(dinv, n);
    scanA<<<nbA, 256, 0, stream>>>(cnt, rowptr, bsum, n);
    scanB<<<1, 512, 0, stream>>>(bsum, nbA);
    scanC<<<nbA, 256, 0, stream>>>(rowptr, bsum, cursor, n);
    place_kernel<<<(E + 255) / 256, 256, 0, stream>>>(row, col, ew, dinv, cursor, srow, snorm, E);

    const int gemm_grid = (n + 15) / 16;
    const int gath_grid = (n + 3) / 4;

    // ---- layer 1: hA = relu(conv(x, W_in, b_in)) ----
    gemm_n64<<<gemm_grid, 256, 0, stream>>>(x, W_in, hw, n);
    gather64_kernel<<<gath_grid, 256, 0, stream>>>(rowptr, cnt, srow, snorm, hw, dinv, b_in, nullptr, hA, n);

    // ---- layer 2: hB = relu(conv(hA, W1, b1) + hA) ----
    gemm_n64<<<gemm_grid, 256, 0, stream>>>(hA, W1, hw, n);
    gather64_kernel<<<gath_grid, 256, 0, stream>>>(rowptr, cnt, srow, snorm, hw, dinv, b1, hA, hB, n);

    // ---- layer 3: hA = relu(conv(hB, W2, b2) + hB) ----
    gemm_n64<<<gemm_grid, 256, 0, stream>>>(hB, W2, hw, n);
    gather64_kernel<<<gath_grid, 256, 0, stream>>>(rowptr, cnt, srow, snorm, hw, dinv, b2, hB, hA, n);

    // ---- final: out = conv(hA, Wf, bf)  [N,1] ----
    gemv_final<<<gath_grid, 256, 0, stream>>>(hA, Wf, hwf, n);
    gather1_kernel<<<(n + 255) / 256, 256, 0, stream>>>(rowptr, cnt, srow, snorm, hwf, dinv, bf, out, n);
}

// Round 3
// 447.048 us; speedup vs baseline: 2.4244x; 1.4665x over previous
//
#include <hip/hip_runtime.h>

#define NN 100000
#define NE 1000000
#define D 64

__device__ __forceinline__ float bf2f(unsigned short u) {
    return __uint_as_float(((unsigned int)u) << 16);
}
__device__ __forceinline__ unsigned short f2bf(float f) {
    unsigned int u = __float_as_uint(f);
    u += 0x7fffu + ((u >> 16) & 1u);   // round-to-nearest-even
    return (unsigned short)(u >> 16);
}

// ---------------- pass 1: per-col count + position ----------------
__global__ void count_pos_kernel(const int* __restrict__ col, int* __restrict__ cnt,
                                 int* __restrict__ epos, int E) {
    int e = blockIdx.x * blockDim.x + threadIdx.x;
    if (e < E) epos[e] = atomicAdd(&cnt[col[e]], 1);
}

// ---------------- two-level exclusive scan of cnt -> rowptr ----------------
__global__ void scanA(const int* __restrict__ cnt, int* __restrict__ rowptr,
                      int* __restrict__ bsum, int n) {
    __shared__ int s[256];
    int t = threadIdx.x;
    int i = blockIdx.x * 256 + t;
    int orig = (i < n) ? cnt[i] : 0;
    s[t] = orig;
    __syncthreads();
#pragma unroll
    for (int o = 1; o < 256; o <<= 1) {
        int v = (t >= o) ? s[t - o] : 0;
        __syncthreads();
        s[t] += v;
        __syncthreads();
    }
    if (i < n) rowptr[i] = s[t] - orig;
    if (t == 255) bsum[blockIdx.x] = s[t];
}

__global__ void scanB(int* __restrict__ bsum, int nb) {
    __shared__ int s[512];
    int t = threadIdx.x;
    int orig = (t < nb) ? bsum[t] : 0;
    s[t] = orig;
    __syncthreads();
#pragma unroll
    for (int o = 1; o < 512; o <<= 1) {
        int v = (t >= o) ? s[t - o] : 0;
        __syncthreads();
        s[t] += v;
        __syncthreads();
    }
    if (t < nb) bsum[t] = s[t] - orig;
}

__global__ void scanC(int* __restrict__ rowptr, const int* __restrict__ bsum, int n) {
    int i = blockIdx.x * 256 + threadIdx.x;
    if (i < n) rowptr[i] += bsum[i >> 8];
}

// ---------------- pass 2: atomic-free placement (sorted by col) ----------------
// sedge[p] = {src_row, bits(edge_weight)}
__global__ void place_kernel(const int* __restrict__ row, const int* __restrict__ col,
                             const float* __restrict__ ew, const int* __restrict__ epos,
                             const int* __restrict__ rowptr, int2* __restrict__ sedge, int E) {
    int e = blockIdx.x * blockDim.x + threadIdx.x;
    if (e < E) {
        int c = col[e];
        int p = rowptr[c] + epos[e];
        sedge[p] = make_int2(row[e], __float_as_int(ew[e]));
    }
}

// ---------------- per-node weighted degree -> dinv ----------------
__global__ void dinv_kernel(const int* __restrict__ rowptr, const int* __restrict__ cnt,
                            const int2* __restrict__ sedge, float* __restrict__ dinv, int n) {
    int i = blockIdx.x * blockDim.x + threadIdx.x;
    if (i >= n) return;
    int s = rowptr[i], d = cnt[i];
    float sum = 1.0f;  // self loop weight
    for (int e = s; e < s + d; ++e) sum += __int_as_float(sedge[e].y);
    dinv[i] = rsqrtf(sum);
}

// ---------------- rewrite sedge.y = full norm = dinv[r]*ew*dinv[c] ----------------
__global__ void wscale_kernel(const int* __restrict__ rowptr, const int* __restrict__ cnt,
                              int2* __restrict__ sedge, const float* __restrict__ dinv, int n) {
    int c = blockIdx.x * blockDim.x + threadIdx.x;
    if (c >= n) return;
    int s = rowptr[c], d = cnt[c];
    float dc = dinv[c];
    for (int e = s; e < s + d; ++e) {
        int2 ed = sedge[e];
        float w = __int_as_float(ed.y) * dinv[ed.x] * dc;
        sedge[e] = make_int2(ed.x, __float_as_int(w));
    }
}

// ---------------- dense transform: out16[n][64] (bf16) = H[n,:] @ W ----------------
__global__ void gemm_n64_bf16(const float* __restrict__ H, const float* __restrict__ W,
                              unsigned short* __restrict__ out16, int n) {
    __shared__ float Ws[D][D];
    __shared__ float Hs[16][D];
    int tid = threadIdx.x;
    for (int i = tid; i < D * D; i += 256) Ws[i >> 6][i & 63] = W[i];
    int base = blockIdx.x * 16;
    for (int i = tid; i < 16 * D; i += 256) {
        int r = i >> 6, k = i & 63;
        int node = base + r;
        Hs[r][k] = (node < n) ? H[node * D + k] : 0.0f;
    }
    __syncthreads();
    int j = tid & 63;
    int r0 = tid >> 6;
#pragma unroll
    for (int rr = 0; rr < 4; ++rr) {
        int r = r0 * 4 + rr;
        int node = base + r;
        if (node < n) {
            float acc = 0.0f;
#pragma unroll
            for (int k = 0; k < D; ++k) acc = fmaf(Hs[r][k], Ws[k][j], acc);
            out16[node * D + j] = f2bf(acc);
        }
    }
}

// ---------------- fused gather (2 edges/wave, bf16 table) + self + bias + res + relu ----------------
// wave = one dest node; lanes 0-31 handle even-slot edges, 32-63 odd-slot.
// lane (l&31) owns feature pair (2*(l&31), 2*(l&31)+1).
__global__ void gather2_kernel(const int* __restrict__ rowptr, const int* __restrict__ cnt,
                               const int2* __restrict__ sedge,
                               const ushort2* __restrict__ hw16,  // [n][32]
                               const float* __restrict__ dinv, const float* __restrict__ b,
                               const float* __restrict__ hres, float* __restrict__ hout, int n) {
    int c = blockIdx.x * 4 + (threadIdx.x >> 6);
    if (c >= n) return;
    int lane = threadIdx.x & 63;
    int half = lane >> 5;
    int fl = lane & 31;
    int start = rowptr[c];
    int deg = cnt[c];
    float ax = 0.0f, ay = 0.0f;
    for (int base = 0; base < deg; base += 64) {
        int rem = deg - base;
        int mm = rem < 64 ? rem : 64;
        int2 ed = make_int2(0, 0);                  // weight 0.0 pad, row 0 safe
        if (base + lane < deg) ed = sedge[start + base + lane];
        int mr = (mm + 7) & ~7;
        for (int t = 0; t < mr; t += 8) {
            int rr[4]; int wb[4]; ushort2 u[4];
#pragma unroll
            for (int p = 0; p < 4; ++p) {
                int tt = t + 2 * p + half;          // per-lane src lane -> bpermute
                rr[p] = __shfl(ed.x, tt, 64);
                wb[p] = __shfl(ed.y, tt, 64);
                u[p] = hw16[rr[p] * 32 + fl];
            }
#pragma unroll
            for (int p = 0; p < 4; ++p) {
                float w = __int_as_float(wb[p]);
                ax = fmaf(w, bf2f(u[p].x), ax);
                ay = fmaf(w, bf2f(u[p].y), ay);
            }
        }
    }
    // fold the two halves
    ax += __shfl_xor(ax, 32, 64);
    ay += __shfl_xor(ay, 32, 64);
    if (half == 0) {
        float d = dinv[c];
        ushort2 su = hw16[c * 32 + fl];
        float2 bb = ((const float2*)b)[fl];
        float vx = ax + d * d * bf2f(su.x) + bb.x;
        float vy = ay + d * d * bf2f(su.y) + bb.y;
        if (hres) {
            float2 hr = ((const float2*)hres)[c * 32 + fl];
            vx += hr.x; vy += hr.y;
        }
        float2 o;
        o.x = fmaxf(vx, 0.0f);
        o.y = fmaxf(vy, 0.0f);
        ((float2*)hout)[c * 32 + fl] = o;
    }
}

// ---------------- final layer ----------------
__global__ void gemv_final(const float* __restrict__ H, const float* __restrict__ Wf,
                           float* __restrict__ hwf, int n) {
    int node = blockIdx.x * 4 + (threadIdx.x >> 6);
    if (node >= n) return;
    int k = threadIdx.x & 63;
    float v = H[node * D + k] * Wf[k];
#pragma unroll
    for (int off = 32; off > 0; off >>= 1) v += __shfl_down(v, off, 64);
    if (k == 0) hwf[node] = v;
}

__global__ void gather1_kernel(const int* __restrict__ rowptr, const int* __restrict__ cnt,
                               const int2* __restrict__ sedge, const float* __restrict__ hwf,
                               const float* __restrict__ dinv, const float* __restrict__ bf,
                               float* __restrict__ out, int n) {
    int c = blockIdx.x * blockDim.x + threadIdx.x;
    if (c >= n) return;
    int s = rowptr[c];
    int e1 = s + cnt[c];
    float acc = 0.0f;
    for (int e = s; e < e1; ++e) {
        int2 ed = sedge[e];
        acc = fmaf(__int_as_float(ed.y), hwf[ed.x], acc);
    }
    float d = dinv[c];
    out[c] = acc + d * d * hwf[c] + bf[0];
}

extern "C" void kernel_launch(void* const* d_in, const int* in_sizes, int n_in,
                              void* d_out, int out_size, void* d_ws, size_t ws_size,
                              hipStream_t stream) {
    const float* x    = (const float*)d_in[0];
    const int*   ei   = (const int*)d_in[1];      // [2, E] flat: row then col
    const float* ew   = (const float*)d_in[2];
    const float* W_in = (const float*)d_in[4];
    const float* b_in = (const float*)d_in[5];
    const float* W1   = (const float*)d_in[6];
    const float* b1   = (const float*)d_in[7];
    const float* W2   = (const float*)d_in[8];
    const float* b2   = (const float*)d_in[9];
    const float* Wf   = (const float*)d_in[10];
    const float* bf   = (const float*)d_in[11];
    float* out = (float*)d_out;

    const int E = NE, n = NN;
    const int* row = ei;
    const int* col = ei + E;

    // workspace carve-up, 256B-aligned chunks (element size 4B unless noted)
    char* ws = (char*)d_ws;
    size_t off = 0;
    auto alloc = [&](size_t nbytes) {
        void* p = (void*)(ws + off);
        off += ((nbytes + 255) / 256) * 256;
        return p;
    };
    int*   cnt    = (int*)alloc((size_t)n * 4);
    int*   rowptr = (int*)alloc((size_t)n * 4);
    int*   epos   = (int*)alloc((size_t)E * 4);
    int*   bsum   = (int*)alloc(512 * 4);
    int2*  sedge  = (int2*)alloc((size_t)E * 8);
    float* dinv   = (float*)alloc((size_t)n * 4);
    unsigned short* hw16 = (unsigned short*)alloc((size_t)n * D * 2);
    float* hA     = (float*)alloc((size_t)n * D * 4);
    float* hB     = (float*)alloc((size_t)n * D * 4);
    float* hwf    = (float*)alloc((size_t)n * 4);

    const int nbA = (n + 255) / 256;          // 391 <= 512
    const int egrid = (E + 255) / 256;
    const int ngrid = (n + 255) / 256;
    const int gemm_grid = (n + 15) / 16;
    const int wave_grid = (n + 3) / 4;

    // ---- CSR build + norms ----
    hipMemsetAsync(cnt, 0, n * sizeof(int), stream);
    count_pos_kernel<<<egrid, 256, 0, stream>>>(col, cnt, epos, E);
    scanA<<<nbA, 256, 0, stream>>>(cnt, rowptr, bsum, n);
    scanB<<<1, 512, 0, stream>>>(bsum, nbA);
    scanC<<<nbA, 256, 0, stream>>>(rowptr, bsum, n);
    place_kernel<<<egrid, 256, 0, stream>>>(row, col, ew, epos, rowptr, sedge, E);
    dinv_kernel<<<ngrid, 256, 0, stream>>>(rowptr, cnt, sedge, dinv, n);
    wscale_kernel<<<ngrid, 256, 0, stream>>>(rowptr, cnt, sedge, dinv, n);

    // ---- layer 1: hA = relu(conv(x, W_in, b_in)) ----
    gemm_n64_bf16<<<gemm_grid, 256, 0, stream>>>(x, W_in, hw16, n);
    gather2_kernel<<<wave_grid, 256, 0, stream>>>(rowptr, cnt, sedge, (const ushort2*)hw16,
                                                  dinv, b_in, nullptr, hA, n);

    // ---- layer 2: hB = relu(conv(hA, W1, b1) + hA) ----
    gemm_n64_bf16<<<gemm_grid, 256, 0, stream>>>(hA, W1, hw16, n);
    gather2_kernel<<<wave_grid, 256, 0, stream>>>(rowptr, cnt, sedge, (const ushort2*)hw16,
                                                  dinv, b1, hA, hB, n);

    // ---- layer 3: hA = relu(conv(hB, W2, b2) + hB) ----
    gemm_n64_bf16<<<gemm_grid, 256, 0, stream>>>(hB, W2, hw16, n);
    gather2_kernel<<<wave_grid, 256, 0, stream>>>(rowptr, cnt, sedge, (const ushort2*)hw16,
                                                  dinv, b2, hB, hA, n);

    // ---- final: out = conv(hA, Wf, bf)  [N,1] ----
    gemv_final<<<wave_grid, 256, 0, stream>>>(hA, Wf, hwf, n);
    gather1_kernel<<<ngrid, 256, 0, stream>>>(rowptr, cnt, sedge, hwf, dinv, bf, out, n);
}

// Round 5
// 365.638 us; speedup vs baseline: 2.9642x; 1.2227x over previous
//
#include <hip/hip_runtime.h>

#define NN 100000
#define NE 1000000
#define D 64

using short8 = __attribute__((ext_vector_type(8))) short;
using f32x4  = __attribute__((ext_vector_type(4))) float;

__device__ __forceinline__ float bf2f(unsigned short u) {
    return __uint_as_float(((unsigned int)u) << 16);
}
__device__ __forceinline__ unsigned short f2bf(float f) {
    unsigned int u = __float_as_uint(f);
    u += 0x7fffu + ((u >> 16) & 1u);   // round-to-nearest-even
    return (unsigned short)(u >> 16);
}

// ---------------- pass 1: per-col count + position ----------------
__global__ void count_pos_kernel(const int* __restrict__ col, int* __restrict__ cnt,
                                 int* __restrict__ epos, int E) {
    int e = blockIdx.x * blockDim.x + threadIdx.x;
    if (e < E) epos[e] = atomicAdd(&cnt[col[e]], 1);
}

// ---------------- two-level exclusive scan of cnt -> rowptr ----------------
__global__ void scanA(const int* __restrict__ cnt, int* __restrict__ rowptr,
                      int* __restrict__ bsum, int n) {
    __shared__ int s[256];
    int t = threadIdx.x;
    int i = blockIdx.x * 256 + t;
    int orig = (i < n) ? cnt[i] : 0;
    s[t] = orig;
    __syncthreads();
#pragma unroll
    for (int o = 1; o < 256; o <<= 1) {
        int v = (t >= o) ? s[t - o] : 0;
        __syncthreads();
        s[t] += v;
        __syncthreads();
    }
    if (i < n) rowptr[i] = s[t] - orig;
    if (t == 255) bsum[blockIdx.x] = s[t];
}

__global__ void scanB(int* __restrict__ bsum, int nb) {
    __shared__ int s[512];
    int t = threadIdx.x;
    int orig = (t < nb) ? bsum[t] : 0;
    s[t] = orig;
    __syncthreads();
#pragma unroll
    for (int o = 1; o < 512; o <<= 1) {
        int v = (t >= o) ? s[t - o] : 0;
        __syncthreads();
        s[t] += v;
        __syncthreads();
    }
    if (t < nb) bsum[t] = s[t] - orig;
}

__global__ void scanC(int* __restrict__ rowptr, const int* __restrict__ bsum, int n) {
    int i = blockIdx.x * 256 + threadIdx.x;
    if (i < n) rowptr[i] += bsum[i >> 8];
}

// ---------------- pass 2: atomic-free placement (sorted by col) ----------------
__global__ void place_kernel(const int* __restrict__ row, const int* __restrict__ col,
                             const float* __restrict__ ew, const int* __restrict__ epos,
                             const int* __restrict__ rowptr, int2* __restrict__ sedge, int E) {
    int e = blockIdx.x * blockDim.x + threadIdx.x;
    if (e < E) {
        int c = col[e];
        int p = rowptr[c] + epos[e];
        sedge[p] = make_int2(row[e], __float_as_int(ew[e]));
    }
}

// ---------------- per-node weighted degree -> dinv ----------------
__global__ void dinv_kernel(const int* __restrict__ rowptr, const int* __restrict__ cnt,
                            const int2* __restrict__ sedge, float* __restrict__ dinv, int n) {
    int i = blockIdx.x * blockDim.x + threadIdx.x;
    if (i >= n) return;
    int s = rowptr[i], d = cnt[i];
    float sum = 1.0f;  // self loop weight
    for (int e = s; e < s + d; ++e) sum += __int_as_float(sedge[e].y);
    dinv[i] = rsqrtf(sum);
}

// ---------------- rewrite sedge.y = full norm = dinv[r]*ew*dinv[c] ----------------
__global__ void wscale_kernel(const int* __restrict__ rowptr, const int* __restrict__ cnt,
                              int2* __restrict__ sedge, const float* __restrict__ dinv, int n) {
    int c = blockIdx.x * blockDim.x + threadIdx.x;
    if (c >= n) return;
    int s = rowptr[c], d = cnt[c];
    float dc = dinv[c];
    for (int e = s; e < s + d; ++e) {
        int2 ed = sedge[e];
        float w = __int_as_float(ed.y) * dinv[ed.x] * dc;
        sedge[e] = make_int2(ed.x, __float_as_int(w));
    }
}

// ---------------- weight transpose+bf16: Wt[j][k] = bf16(W[k][j]), 3 layers ----------------
__global__ void wtrans3(const float* __restrict__ W0, const float* __restrict__ W1,
                        const float* __restrict__ W2, unsigned short* __restrict__ T0,
                        unsigned short* __restrict__ T1, unsigned short* __restrict__ T2) {
    int b = blockIdx.x >> 4;                          // 0..2 = which layer
    int i = (blockIdx.x & 15) * 256 + threadIdx.x;    // 0..4095
    const float* W = (b == 0) ? W0 : (b == 1) ? W1 : W2;
    unsigned short* T = (b == 0) ? T0 : (b == 1) ? T1 : T2;
    int k = i >> 6, j = i & 63;
    T[j * 64 + k] = f2bf(W[k * 64 + j]);
}

// ---------------- MFMA dense transform: out16[n][64] (bf16) = H @ W ----------------
// block = 4 waves = 64 rows; wave = 16 rows x 64 cols via 8x mfma_f32_16x16x32_bf16.
// A: lane holds H[base+(l&15)][8*(l>>4)+i]; B: Wt[jt*16+(l&15)][8*(l>>4)+i];
// D: row = 4*(l>>4)+i, col = l&15  (m89-verified mapping).
__global__ __launch_bounds__(256) void gemm_mfma(const float* __restrict__ H,
                                                 const unsigned short* __restrict__ Wt,
                                                 unsigned short* __restrict__ out16, int n) {
    int wave = threadIdx.x >> 6;
    int lane = threadIdx.x & 63;
    int r = lane & 15;
    int kg = lane >> 4;
    int base = blockIdx.x * 64 + wave * 16;
    int node = base + r;
    bool rv = node < n;
    const float* hrow = H + (size_t)(rv ? node : 0) * D;

    short8 a[2];
#pragma unroll
    for (int kk = 0; kk < 2; ++kk) {
        float4 f0, f1;
        if (rv) {
            f0 = *(const float4*)(hrow + kk * 32 + kg * 8);
            f1 = *(const float4*)(hrow + kk * 32 + kg * 8 + 4);
        } else {
            f0 = make_float4(0.f, 0.f, 0.f, 0.f);
            f1 = f0;
        }
        short8 v;
        v[0] = (short)f2bf(f0.x); v[1] = (short)f2bf(f0.y);
        v[2] = (short)f2bf(f0.z); v[3] = (short)f2bf(f0.w);
        v[4] = (short)f2bf(f1.x); v[5] = (short)f2bf(f1.y);
        v[6] = (short)f2bf(f1.z); v[7] = (short)f2bf(f1.w);
        a[kk] = v;
    }

    f32x4 acc[4];
#pragma unroll
    for (int jt = 0; jt < 4; ++jt) acc[jt] = (f32x4){0.f, 0.f, 0.f, 0.f};

#pragma unroll
    for (int jt = 0; jt < 4; ++jt) {
        short8 b0 = *(const short8*)(Wt + ((jt * 16 + r) * 64 + kg * 8));
        short8 b1 = *(const short8*)(Wt + ((jt * 16 + r) * 64 + 32 + kg * 8));
        acc[jt] = __builtin_amdgcn_mfma_f32_16x16x32_bf16(a[0], b0, acc[jt], 0, 0, 0);
        acc[jt] = __builtin_amdgcn_mfma_f32_16x16x32_bf16(a[1], b1, acc[jt], 0, 0, 0);
    }

#pragma unroll
    for (int i = 0; i < 4; ++i) {
        int orow = base + 4 * kg + i;
        if (orow < n) {
            unsigned short* o = out16 + (size_t)orow * D + r;
#pragma unroll
            for (int jt = 0; jt < 4; ++jt) o[jt * 16] = f2bf(acc[jt][i]);
        }
    }
}

// ---------------- fused gather (2 edges/wave, bf16 table) + self + bias + res + relu ----------------
__global__ void gather2_kernel(const int* __restrict__ rowptr, const int* __restrict__ cnt,
                               const int2* __restrict__ sedge,
                               const ushort2* __restrict__ hw16,  // [n][32]
                               const float* __restrict__ dinv, const float* __restrict__ b,
                               const float* __restrict__ hres, float* __restrict__ hout, int n) {
    int c = blockIdx.x * 4 + (threadIdx.x >> 6);
    if (c >= n) return;
    int lane = threadIdx.x & 63;
    int half = lane >> 5;
    int fl = lane & 31;
    int start = rowptr[c];
    int deg = cnt[c];
    float ax = 0.0f, ay = 0.0f;
    for (int base = 0; base < deg; base += 64) {
        int rem = deg - base;
        int mm = rem < 64 ? rem : 64;
        int2 ed = make_int2(0, 0);
        if (base + lane < deg) ed = sedge[start + base + lane];
        int mr = (mm + 7) & ~7;
        for (int t = 0; t < mr; t += 8) {
            int rr[4]; int wb[4]; ushort2 u[4];
#pragma unroll
            for (int p = 0; p < 4; ++p) {
                int tt = t + 2 * p + half;
                rr[p] = __shfl(ed.x, tt, 64);
                wb[p] = __shfl(ed.y, tt, 64);
                u[p] = hw16[rr[p] * 32 + fl];
            }
#pragma unroll
            for (int p = 0; p < 4; ++p) {
                float w = __int_as_float(wb[p]);
                ax = fmaf(w, bf2f(u[p].x), ax);
                ay = fmaf(w, bf2f(u[p].y), ay);
            }
        }
    }
    ax += __shfl_xor(ax, 32, 64);
    ay += __shfl_xor(ay, 32, 64);
    if (half == 0) {
        float d = dinv[c];
        ushort2 su = hw16[c * 32 + fl];
        float2 bb = ((const float2*)b)[fl];
        float vx = ax + d * d * bf2f(su.x) + bb.x;
        float vy = ay + d * d * bf2f(su.y) + bb.y;
        if (hres) {
            float2 hr = ((const float2*)hres)[c * 32 + fl];
            vx += hr.x; vy += hr.y;
        }
        float2 o;
        o.x = fmaxf(vx, 0.0f);
        o.y = fmaxf(vy, 0.0f);
        ((float2*)hout)[c * 32 + fl] = o;
    }
}

// ---------------- final layer ----------------
__global__ void gemv_final(const float* __restrict__ H, const float* __restrict__ Wf,
                           float* __restrict__ hwf, int n) {
    int node = blockIdx.x * 4 + (threadIdx.x >> 6);
    if (node >= n) return;
    int k = threadIdx.x & 63;
    float v = H[node * D + k] * Wf[k];
#pragma unroll
    for (int off = 32; off > 0; off >>= 1) v += __shfl_down(v, off, 64);
    if (k == 0) hwf[node] = v;
}

__global__ void gather1_kernel(const int* __restrict__ rowptr, const int* __restrict__ cnt,
                               const int2* __restrict__ sedge, const float* __restrict__ hwf,
                               const float* __restrict__ dinv, const float* __restrict__ bf,
                               float* __restrict__ out, int n) {
    int c = blockIdx.x * blockDim.x + threadIdx.x;
    if (c >= n) return;
    int s = rowptr[c];
    int e1 = s + cnt[c];
    float acc = 0.0f;
    for (int e = s; e < e1; ++e) {
        int2 ed = sedge[e];
        acc = fmaf(__int_as_float(ed.y), hwf[ed.x], acc);
    }
    float d = dinv[c];
    out[c] = acc + d * d * hwf[c] + bf[0];
}

extern "C" void kernel_launch(void* const* d_in, const int* in_sizes, int n_in,
                              void* d_out, int out_size, void* d_ws, size_t ws_size,
                              hipStream_t stream) {
    const float* x    = (const float*)d_in[0];
    const int*   ei   = (const int*)d_in[1];      // [2, E] flat: row then col
    const float* ew   = (const float*)d_in[2];
    const float* W_in = (const float*)d_in[4];
    const float* b_in = (const float*)d_in[5];
    const float* W1   = (const float*)d_in[6];
    const float* b1   = (const float*)d_in[7];
    const float* W2   = (const float*)d_in[8];
    const float* b2   = (const float*)d_in[9];
    const float* Wf   = (const float*)d_in[10];
    const float* bf   = (const float*)d_in[11];
    float* out = (float*)d_out;

    const int E = NE, n = NN;
    const int* row = ei;
    const int* col = ei + E;

    char* ws = (char*)d_ws;
    size_t off = 0;
    auto alloc = [&](size_t nbytes) {
        void* p = (void*)(ws + off);
        off += ((nbytes + 255) / 256) * 256;
        return p;
    };
    int*   cnt    = (int*)alloc((size_t)n * 4);
    int*   rowptr = (int*)alloc((size_t)n * 4);
    int*   epos   = (int*)alloc((size_t)E * 4);
    int*   bsum   = (int*)alloc(512 * 4);
    int2*  sedge  = (int2*)alloc((size_t)E * 8);
    float* dinv   = (float*)alloc((size_t)n * 4);
    unsigned short* hw16 = (unsigned short*)alloc((size_t)n * D * 2);
    float* hA     = (float*)alloc((size_t)n * D * 4);
    float* hB     = (float*)alloc((size_t)n * D * 4);
    float* hwf    = (float*)alloc((size_t)n * 4);
    unsigned short* Wt0 = (unsigned short*)alloc(D * D * 2);
    unsigned short* Wt1 = (unsigned short*)alloc(D * D * 2);
    unsigned short* Wt2 = (unsigned short*)alloc(D * D * 2);

    const int nbA = (n + 255) / 256;          // 391 <= 512
    const int egrid = (E + 255) / 256;
    const int ngrid = (n + 255) / 256;
    const int mfma_grid = (n + 63) / 64;
    const int wave_grid = (n + 3) / 4;

    // ---- weight prep (independent of CSR) ----
    wtrans3<<<48, 256, 0, stream>>>(W_in, W1, W2, Wt0, Wt1, Wt2);

    // ---- CSR build + norms ----
    hipMemsetAsync(cnt, 0, n * sizeof(int), stream);
    count_pos_kernel<<<egrid, 256, 0, stream>>>(col, cnt, epos, E);
    scanA<<<nbA, 256, 0, stream>>>(cnt, rowptr, bsum, n);
    scanB<<<1, 512, 0, stream>>>(bsum, nbA);
    scanC<<<nbA, 256, 0, stream>>>(rowptr, bsum, n);
    place_kernel<<<egrid, 256, 0, stream>>>(row, col, ew, epos, rowptr, sedge, E);
    dinv_kernel<<<ngrid, 256, 0, stream>>>(rowptr, cnt, sedge, dinv, n);
    wscale_kernel<<<ngrid, 256, 0, stream>>>(rowptr, cnt, sedge, dinv, n);

    // ---- layer 1: hA = relu(conv(x, W_in, b_in)) ----
    gemm_mfma<<<mfma_grid, 256, 0, stream>>>(x, Wt0, hw16, n);
    gather2_kernel<<<wave_grid, 256, 0, stream>>>(rowptr, cnt, sedge, (const ushort2*)hw16,
                                                  dinv, b_in, nullptr, hA, n);

    // ---- layer 2: hB = relu(conv(hA, W1, b1) + hA) ----
    gemm_mfma<<<mfma_grid, 256, 0, stream>>>(hA, Wt1, hw16, n);
    gather2_kernel<<<wave_grid, 256, 0, stream>>>(rowptr, cnt, sedge, (const ushort2*)hw16,
                                                  dinv, b1, hA, hB, n);

    // ---- layer 3: hA = relu(conv(hB, W2, b2) + hB) ----
    gemm_mfma<<<mfma_grid, 256, 0, stream>>>(hB, Wt2, hw16, n);
    gather2_kernel<<<wave_grid, 256, 0, stream>>>(rowptr, cnt, sedge, (const ushort2*)hw16,
                                                  dinv, b2, hB, hA, n);

    // ---- final: out = conv(hA, Wf, bf)  [N,1] ----
    gemv_final<<<wave_grid, 256, 0, stream>>>(hA, Wf, hwf, n);
    gather1_kernel<<<ngrid, 256, 0, stream>>>(rowptr, cnt, sedge, hwf, dinv, bf, out, n);
}

// Round 6
// 348.339 us; speedup vs baseline: 3.1114x; 1.0497x over previous
//
#include <hip/hip_runtime.h>

#define NN 100000
#define NE 1000000
#define D 64

using short8 = __attribute__((ext_vector_type(8))) short;
using f32x4  = __attribute__((ext_vector_type(4))) float;

__device__ __forceinline__ float bf2f(unsigned short u) {
    return __uint_as_float(((unsigned int)u) << 16);
}
__device__ __forceinline__ unsigned short f2bf(float f) {
    unsigned int u = __float_as_uint(f);
    u += 0x7fffu + ((u >> 16) & 1u);   // round-to-nearest-even
    return (unsigned short)(u >> 16);
}

// ---------------- pass 1: per-col count + position ----------------
__global__ void count_pos_kernel(const int* __restrict__ col, int* __restrict__ cnt,
                                 int* __restrict__ epos, int E) {
    int e = blockIdx.x * blockDim.x + threadIdx.x;
    if (e < E) epos[e] = atomicAdd(&cnt[col[e]], 1);
}

// ---------------- two-level exclusive scan of cnt -> rowptr ----------------
__global__ void scanA(const int* __restrict__ cnt, int* __restrict__ rowptr,
                      int* __restrict__ bsum, int n) {
    __shared__ int s[256];
    int t = threadIdx.x;
    int i = blockIdx.x * 256 + t;
    int orig = (i < n) ? cnt[i] : 0;
    s[t] = orig;
    __syncthreads();
#pragma unroll
    for (int o = 1; o < 256; o <<= 1) {
        int v = (t >= o) ? s[t - o] : 0;
        __syncthreads();
        s[t] += v;
        __syncthreads();
    }
    if (i < n) rowptr[i] = s[t] - orig;
    if (t == 255) bsum[blockIdx.x] = s[t];
}

__global__ void scanB(int* __restrict__ bsum, int nb) {
    __shared__ int s[512];
    int t = threadIdx.x;
    int orig = (t < nb) ? bsum[t] : 0;
    s[t] = orig;
    __syncthreads();
#pragma unroll
    for (int o = 1; o < 512; o <<= 1) {
        int v = (t >= o) ? s[t - o] : 0;
        __syncthreads();
        s[t] += v;
        __syncthreads();
    }
    if (t < nb) bsum[t] = s[t] - orig;
}

__global__ void scanC(int* __restrict__ rowptr, const int* __restrict__ bsum, int n) {
    int i = blockIdx.x * 256 + threadIdx.x;
    if (i < n) rowptr[i] += bsum[i >> 8];
}

// ---------------- pass 2: atomic-free placement (sorted by col) ----------------
__global__ void place_kernel(const int* __restrict__ row, const int* __restrict__ col,
                             const float* __restrict__ ew, const int* __restrict__ epos,
                             const int* __restrict__ rowptr, int2* __restrict__ sedge, int E) {
    int e = blockIdx.x * blockDim.x + threadIdx.x;
    if (e < E) {
        int c = col[e];
        int p = rowptr[c] + epos[e];
        sedge[p] = make_int2(row[e], __float_as_int(ew[e]));
    }
}

// ---------------- per-node weighted degree -> dinv ----------------
__global__ void dinv_kernel(const int* __restrict__ rowptr, const int* __restrict__ cnt,
                            const int2* __restrict__ sedge, float* __restrict__ dinv, int n) {
    int i = blockIdx.x * blockDim.x + threadIdx.x;
    if (i >= n) return;
    int s = rowptr[i], d = cnt[i];
    float sum = 1.0f;  // self loop weight
    for (int e = s; e < s + d; ++e) sum += __int_as_float(sedge[e].y);
    dinv[i] = rsqrtf(sum);
}

// ---------------- rewrite sedge.y = full norm = dinv[r]*ew*dinv[c] ----------------
__global__ void wscale_kernel(const int* __restrict__ rowptr, const int* __restrict__ cnt,
                              int2* __restrict__ sedge, const float* __restrict__ dinv, int n) {
    int c = blockIdx.x * blockDim.x + threadIdx.x;
    if (c >= n) return;
    int s = rowptr[c], d = cnt[c];
    float dc = dinv[c];
    for (int e = s; e < s + d; ++e) {
        int2 ed = sedge[e];
        float w = __int_as_float(ed.y) * dinv[ed.x] * dc;
        sedge[e] = make_int2(ed.x, __float_as_int(w));
    }
}

// ---------------- weight transpose+bf16: Wt[j][k] = bf16(W[k][j]), 3 layers ----------------
__global__ void wtrans3(const float* __restrict__ W0, const float* __restrict__ W1,
                        const float* __restrict__ W2, unsigned short* __restrict__ T0,
                        unsigned short* __restrict__ T1, unsigned short* __restrict__ T2) {
    int b = blockIdx.x >> 4;                          // 0..2 = which layer
    int i = (blockIdx.x & 15) * 256 + threadIdx.x;    // 0..4095
    const float* W = (b == 0) ? W0 : (b == 1) ? W1 : W2;
    unsigned short* T = (b == 0) ? T0 : (b == 1) ? T1 : T2;
    int k = i >> 6, j = i & 63;
    T[j * 64 + k] = f2bf(W[k * 64 + j]);
}

// ---------------- MFMA dense transform: out16[n][64] (bf16) = H @ W ----------------
__global__ __launch_bounds__(256) void gemm_mfma(const float* __restrict__ H,
                                                 const unsigned short* __restrict__ Wt,
                                                 unsigned short* __restrict__ out16, int n) {
    int wave = threadIdx.x >> 6;
    int lane = threadIdx.x & 63;
    int r = lane & 15;
    int kg = lane >> 4;
    int base = blockIdx.x * 64 + wave * 16;
    int node = base + r;
    bool rv = node < n;
    const float* hrow = H + (size_t)(rv ? node : 0) * D;

    short8 a[2];
#pragma unroll
    for (int kk = 0; kk < 2; ++kk) {
        float4 f0, f1;
        if (rv) {
            f0 = *(const float4*)(hrow + kk * 32 + kg * 8);
            f1 = *(const float4*)(hrow + kk * 32 + kg * 8 + 4);
        } else {
            f0 = make_float4(0.f, 0.f, 0.f, 0.f);
            f1 = f0;
        }
        short8 v;
        v[0] = (short)f2bf(f0.x); v[1] = (short)f2bf(f0.y);
        v[2] = (short)f2bf(f0.z); v[3] = (short)f2bf(f0.w);
        v[4] = (short)f2bf(f1.x); v[5] = (short)f2bf(f1.y);
        v[6] = (short)f2bf(f1.z); v[7] = (short)f2bf(f1.w);
        a[kk] = v;
    }

    f32x4 acc[4];
#pragma unroll
    for (int jt = 0; jt < 4; ++jt) acc[jt] = (f32x4){0.f, 0.f, 0.f, 0.f};

#pragma unroll
    for (int jt = 0; jt < 4; ++jt) {
        short8 b0 = *(const short8*)(Wt + ((jt * 16 + r) * 64 + kg * 8));
        short8 b1 = *(const short8*)(Wt + ((jt * 16 + r) * 64 + 32 + kg * 8));
        acc[jt] = __builtin_amdgcn_mfma_f32_16x16x32_bf16(a[0], b0, acc[jt], 0, 0, 0);
        acc[jt] = __builtin_amdgcn_mfma_f32_16x16x32_bf16(a[1], b1, acc[jt], 0, 0, 0);
    }

#pragma unroll
    for (int i = 0; i < 4; ++i) {
        int orow = base + 4 * kg + i;
        if (orow < n) {
            unsigned short* o = out16 + (size_t)orow * D + r;
#pragma unroll
            for (int jt = 0; jt < 4; ++jt) o[jt * 16] = f2bf(acc[jt][i]);
        }
    }
}

// ---------------- fused gather (4 edges/wave, ushort4 row slices) ----------------
// wave = one dest node; quarter q=lane>>4 handles edge slot t+p*4+q; lane fl=lane&15
// owns features 4fl..4fl+3. 4 independent 128B row loads in flight per chunk.
__global__ void gather4_kernel(const int* __restrict__ rowptr, const int* __restrict__ cnt,
                               const int2* __restrict__ sedge,
                               const ushort4* __restrict__ hw16,  // [n][16] x (4 bf16)
                               const float* __restrict__ dinv, const float* __restrict__ b,
                               const float* __restrict__ hres, float* __restrict__ hout, int n) {
    int c = blockIdx.x * 4 + (threadIdx.x >> 6);
    if (c >= n) return;
    int lane = threadIdx.x & 63;
    int q = lane >> 4;
    int fl = lane & 15;
    int start = rowptr[c];
    int deg = cnt[c];
    float ax = 0.f, ay = 0.f, az = 0.f, aw = 0.f;
    for (int base = 0; base < deg; base += 64) {
        int rem = deg - base;
        int mm = rem < 64 ? rem : 64;
        int2 ed = make_int2(0, 0);                 // pad: row 0, weight 0.0
        if (base + lane < deg) ed = sedge[start + base + lane];
        int mr = (mm + 15) & ~15;
        for (int t = 0; t < mr; t += 16) {
            int rr[4]; int wb[4]; ushort4 u[4];
#pragma unroll
            for (int p = 0; p < 4; ++p) {
                int tt = t + p * 4 + q;
                rr[p] = __shfl(ed.x, tt, 64);
                wb[p] = __shfl(ed.y, tt, 64);
                u[p] = hw16[rr[p] * 16 + fl];
            }
#pragma unroll
            for (int p = 0; p < 4; ++p) {
                float w = __int_as_float(wb[p]);
                ax = fmaf(w, bf2f(u[p].x), ax);
                ay = fmaf(w, bf2f(u[p].y), ay);
                az = fmaf(w, bf2f(u[p].z), az);
                aw = fmaf(w, bf2f(u[p].w), aw);
            }
        }
    }
    // fold the four quarters
    ax += __shfl_xor(ax, 16, 64); ay += __shfl_xor(ay, 16, 64);
    az += __shfl_xor(az, 16, 64); aw += __shfl_xor(aw, 16, 64);
    ax += __shfl_xor(ax, 32, 64); ay += __shfl_xor(ay, 32, 64);
    az += __shfl_xor(az, 32, 64); aw += __shfl_xor(aw, 32, 64);
    if (lane < 16) {
        float d = dinv[c];
        float dd = d * d;
        ushort4 su = hw16[c * 16 + fl];
        float4 bb = ((const float4*)b)[fl];
        float vx = ax + dd * bf2f(su.x) + bb.x;
        float vy = ay + dd * bf2f(su.y) + bb.y;
        float vz = az + dd * bf2f(su.z) + bb.z;
        float vw = aw + dd * bf2f(su.w) + bb.w;
        if (hres) {
            float4 hr = ((const float4*)hres)[c * 16 + fl];
            vx += hr.x; vy += hr.y; vz += hr.z; vw += hr.w;
        }
        float4 o;
        o.x = fmaxf(vx, 0.0f); o.y = fmaxf(vy, 0.0f);
        o.z = fmaxf(vz, 0.0f); o.w = fmaxf(vw, 0.0f);
        ((float4*)hout)[c * 16 + fl] = o;
    }
}

// ---------------- layer-3 gather fused with final GEMV: writes hwf[c] only ----------------
__global__ void gather4_final_kernel(const int* __restrict__ rowptr, const int* __restrict__ cnt,
                                     const int2* __restrict__ sedge,
                                     const ushort4* __restrict__ hw16,
                                     const float* __restrict__ dinv, const float* __restrict__ b,
                                     const float* __restrict__ hres,
                                     const float* __restrict__ Wf,
                                     float* __restrict__ hwf, int n) {
    int c = blockIdx.x * 4 + (threadIdx.x >> 6);
    if (c >= n) return;
    int lane = threadIdx.x & 63;
    int q = lane >> 4;
    int fl = lane & 15;
    int start = rowptr[c];
    int deg = cnt[c];
    float ax = 0.f, ay = 0.f, az = 0.f, aw = 0.f;
    for (int base = 0; base < deg; base += 64) {
        int rem = deg - base;
        int mm = rem < 64 ? rem : 64;
        int2 ed = make_int2(0, 0);
        if (base + lane < deg) ed = sedge[start + base + lane];
        int mr = (mm + 15) & ~15;
        for (int t = 0; t < mr; t += 16) {
            int rr[4]; int wb[4]; ushort4 u[4];
#pragma unroll
            for (int p = 0; p < 4; ++p) {
                int tt = t + p * 4 + q;
                rr[p] = __shfl(ed.x, tt, 64);
                wb[p] = __shfl(ed.y, tt, 64);
                u[p] = hw16[rr[p] * 16 + fl];
            }
#pragma unroll
            for (int p = 0; p < 4; ++p) {
                float w = __int_as_float(wb[p]);
                ax = fmaf(w, bf2f(u[p].x), ax);
                ay = fmaf(w, bf2f(u[p].y), ay);
                az = fmaf(w, bf2f(u[p].z), az);
                aw = fmaf(w, bf2f(u[p].w), aw);
            }
        }
    }
    ax += __shfl_xor(ax, 16, 64); ay += __shfl_xor(ay, 16, 64);
    az += __shfl_xor(az, 16, 64); aw += __shfl_xor(aw, 16, 64);
    ax += __shfl_xor(ax, 32, 64); ay += __shfl_xor(ay, 32, 64);
    az += __shfl_xor(az, 32, 64); aw += __shfl_xor(aw, 32, 64);
    // all lanes now hold the full folded acc; compute h value + dot(Wf) per fl
    float d = dinv[c];
    float dd = d * d;
    ushort4 su = hw16[c * 16 + fl];
    float4 bb = ((const float4*)b)[fl];
    float4 hr = ((const float4*)hres)[c * 16 + fl];
    float vx = fmaxf(ax + dd * bf2f(su.x) + bb.x + hr.x, 0.0f);
    float vy = fmaxf(ay + dd * bf2f(su.y) + bb.y + hr.y, 0.0f);
    float vz = fmaxf(az + dd * bf2f(su.z) + bb.z + hr.z, 0.0f);
    float vw = fmaxf(aw + dd * bf2f(su.w) + bb.w + hr.w, 0.0f);
    float4 wf = ((const float4*)Wf)[fl];
    float part = vx * wf.x + vy * wf.y + vz * wf.z + vw * wf.w;
    part += __shfl_xor(part, 8, 16);
    part += __shfl_xor(part, 4, 16);
    part += __shfl_xor(part, 2, 16);
    part += __shfl_xor(part, 1, 16);
    if (lane == 0) hwf[c] = part;
}

__global__ void gather1_kernel(const int* __restrict__ rowptr, const int* __restrict__ cnt,
                               const int2* __restrict__ sedge, const float* __restrict__ hwf,
                               const float* __restrict__ dinv, const float* __restrict__ bf,
                               float* __restrict__ out, int n) {
    int c = blockIdx.x * blockDim.x + threadIdx.x;
    if (c >= n) return;
    int s = rowptr[c];
    int e1 = s + cnt[c];
    float acc = 0.0f;
    for (int e = s; e < e1; ++e) {
        int2 ed = sedge[e];
        acc = fmaf(__int_as_float(ed.y), hwf[ed.x], acc);
    }
    float d = dinv[c];
    out[c] = acc + d * d * hwf[c] + bf[0];
}

extern "C" void kernel_launch(void* const* d_in, const int* in_sizes, int n_in,
                              void* d_out, int out_size, void* d_ws, size_t ws_size,
                              hipStream_t stream) {
    const float* x    = (const float*)d_in[0];
    const int*   ei   = (const int*)d_in[1];      // [2, E] flat: row then col
    const float* ew   = (const float*)d_in[2];
    const float* W_in = (const float*)d_in[4];
    const float* b_in = (const float*)d_in[5];
    const float* W1   = (const float*)d_in[6];
    const float* b1   = (const float*)d_in[7];
    const float* W2   = (const float*)d_in[8];
    const float* b2   = (const float*)d_in[9];
    const float* Wf   = (const float*)d_in[10];
    const float* bf   = (const float*)d_in[11];
    float* out = (float*)d_out;

    const int E = NE, n = NN;
    const int* row = ei;
    const int* col = ei + E;

    char* ws = (char*)d_ws;
    size_t off = 0;
    auto alloc = [&](size_t nbytes) {
        void* p = (void*)(ws + off);
        off += ((nbytes + 255) / 256) * 256;
        return p;
    };
    int*   cnt    = (int*)alloc((size_t)n * 4);
    int*   rowptr = (int*)alloc((size_t)n * 4);
    int*   epos   = (int*)alloc((size_t)E * 4);
    int*   bsum   = (int*)alloc(512 * 4);
    int2*  sedge  = (int2*)alloc((size_t)E * 8);
    float* dinv   = (float*)alloc((size_t)n * 4);
    unsigned short* hw16 = (unsigned short*)alloc((size_t)n * D * 2);
    float* hA     = (float*)alloc((size_t)n * D * 4);
    float* hB     = (float*)alloc((size_t)n * D * 4);
    float* hwf    = (float*)alloc((size_t)n * 4);
    unsigned short* Wt0 = (unsigned short*)alloc(D * D * 2);
    unsigned short* Wt1 = (unsigned short*)alloc(D * D * 2);
    unsigned short* Wt2 = (unsigned short*)alloc(D * D * 2);

    const int nbA = (n + 255) / 256;          // 391 <= 512
    const int egrid = (E + 255) / 256;
    const int ngrid = (n + 255) / 256;
    const int mfma_grid = (n + 63) / 64;
    const int wave_grid = (n + 3) / 4;

    // ---- weight prep (independent of CSR) ----
    wtrans3<<<48, 256, 0, stream>>>(W_in, W1, W2, Wt0, Wt1, Wt2);

    // ---- CSR build + norms ----
    hipMemsetAsync(cnt, 0, n * sizeof(int), stream);
    count_pos_kernel<<<egrid, 256, 0, stream>>>(col, cnt, epos, E);
    scanA<<<nbA, 256, 0, stream>>>(cnt, rowptr, bsum, n);
    scanB<<<1, 512, 0, stream>>>(bsum, nbA);
    scanC<<<nbA, 256, 0, stream>>>(rowptr, bsum, n);
    place_kernel<<<egrid, 256, 0, stream>>>(row, col, ew, epos, rowptr, sedge, E);
    dinv_kernel<<<ngrid, 256, 0, stream>>>(rowptr, cnt, sedge, dinv, n);
    wscale_kernel<<<ngrid, 256, 0, stream>>>(rowptr, cnt, sedge, dinv, n);

    // ---- layer 1: hA = relu(conv(x, W_in, b_in)) ----
    gemm_mfma<<<mfma_grid, 256, 0, stream>>>(x, Wt0, hw16, n);
    gather4_kernel<<<wave_grid, 256, 0, stream>>>(rowptr, cnt, sedge, (const ushort4*)hw16,
                                                  dinv, b_in, nullptr, hA, n);

    // ---- layer 2: hB = relu(conv(hA, W1, b1) + hA) ----
    gemm_mfma<<<mfma_grid, 256, 0, stream>>>(hA, Wt1, hw16, n);
    gather4_kernel<<<wave_grid, 256, 0, stream>>>(rowptr, cnt, sedge, (const ushort4*)hw16,
                                                  dinv, b1, hA, hB, n);

    // ---- layer 3 fused with final GEMV: hwf = relu(conv(hB,W2,b2)+hB) . Wf ----
    gemm_mfma<<<mfma_grid, 256, 0, stream>>>(hB, Wt2, hw16, n);
    gather4_final_kernel<<<wave_grid, 256, 0, stream>>>(rowptr, cnt, sedge, (const ushort4*)hw16,
                                                        dinv, b2, hB, Wf, hwf, n);

    // ---- final propagate: out = A_norm . hwf + bf ----
    gather1_kernel<<<ngrid, 256, 0, stream>>>(rowptr, cnt, sedge, hwf, dinv, bf, out, n);
}